// Round 6
// baseline (414.154 us; speedup 1.0000x reference)
//
#include <hip/hip_runtime.h>

// Problem constants
#define B_ 2
#define N_ 4096
#define H_ 256
#define HEADS_ 4
#define DH_ 64

typedef _Float16 f16;
typedef f16 f16x8 __attribute__((ext_vector_type(8)));
typedef f16 f16x4 __attribute__((ext_vector_type(4)));
typedef float f32x4 __attribute__((ext_vector_type(4)));

// Workspace layout (units: f16 elements)
//  h_h  : 0         2097152   (dead after proj; rsum_ws f32 reuses this region)
//  W_h  : 2097152   4*65536 (Wq,Wk,Wv,Wo)
//  Q_h  : 2359296   2097152   (b,head,n,dh), pre-scaled by 1/8
//  Kf   : 4456448   2097152   fragment-major K: [bh][t][half] 512-f16 frags
//  Vf   : 6553600   2097152   fragment-major V: [bh][jt][ks*4+cg] 512-f16 frags
//  O_h  : 8650752   2097152   (b,n,256)
//  adjb : 10747904  1048576   2 MB packed adjacency bitmask
// total ~24 MB

#define HOUT_OFF 2097152  // float offset of attn part in d_out

__global__ __launch_bounds__(256) void cvt_kernel(
    const float* __restrict__ h, const float* __restrict__ Wq,
    const float* __restrict__ Wk, const float* __restrict__ Wv,
    const float* __restrict__ Wo, f16* __restrict__ ws) {
  int i = blockIdx.x * 256 + threadIdx.x;
  const int NH = 2097152;
  if (i < NH) {
    ws[i] = (f16)h[i];
  } else if (i < NH + 4 * 65536) {
    int j = i - NH;
    int sel = j >> 16;
    int k = j & 65535;
    const float* src = sel == 0 ? Wq : sel == 1 ? Wk : sel == 2 ? Wv : Wo;
    ws[i] = (f16)src[k];
  }
}

// Pack adj (int32 0/1, NxN) into bit-mask: adjb[row*64 + j/64] bit (j&63).
__global__ __launch_bounds__(256) void pack_adj_kernel(
    const int* __restrict__ adj, unsigned long long* __restrict__ adjb) {
  int g = blockIdx.x * 256 + threadIdx.x;
  int lane = threadIdx.x & 63;
  int av = adj[g] != 0;
  unsigned long long m = __ballot(av);
  if (lane == 0) adjb[g >> 6] = m;
}

// QKV projection. grid=(128, 12): y = wsel*4 + head. Block = 4 waves, tile 64x64.
// K and V are written in FRAGMENT-MAJOR layout so attention waves load them as
// contiguous 1 KB bursts (lane*8) instead of 16-line scattered reads.
__global__ __launch_bounds__(256) void proj_kernel(
    const f16* __restrict__ hh, const f16* __restrict__ Wh,
    const float* __restrict__ bq, const float* __restrict__ bk,
    const float* __restrict__ bv, f16* __restrict__ Qh, f16* __restrict__ Kf,
    f16* __restrict__ Vf) {
  const int tid = threadIdx.x;
  const int lane = tid & 63, w = tid >> 6;
  const int q = lane >> 4, c = lane & 15;
  const int wsel = blockIdx.y >> 2, head = blockIdx.y & 3;
  const int m0 = blockIdx.x * 64 + w * 16;
  const f16* W = Wh + wsel * 65536;
  const int o0 = head * 64;

  f32x4 acc[4] = {};
  for (int k0 = 0; k0 < 256; k0 += 32) {
    f16x8 a = *(const f16x8*)(hh + (size_t)(m0 + c) * 256 + k0 + q * 8);
#pragma unroll
    for (int cg = 0; cg < 4; ++cg) {
      f16x8 bfr = *(const f16x8*)(W + (size_t)(o0 + cg * 16 + c) * 256 + k0 + q * 8);
      acc[cg] = __builtin_amdgcn_mfma_f32_16x16x32_f16(a, bfr, acc[cg], 0, 0, 0);
    }
  }
  const int b = m0 >> 12, n = m0 & 4095;
  const int bh2 = b * HEADS_ + head;
  if (wsel == 2) {
    // V fragment-major: Vf[bh][jt][ks*4+cg][lane_f*8+e],
    // lane_f=(jj>>3&3)*16+c, jj = j mod 64, e = jj&7.
    const int jt = n >> 6;
    f16* vbase = Vf + (((size_t)bh2 * 64 + jt) * 8) * 512;
#pragma unroll
    for (int cg = 0; cg < 4; ++cg) {
      float bb = bv[o0 + cg * 16 + c];
#pragma unroll
      for (int r = 0; r < 4; ++r) {
        int jj = w * 16 + q * 4 + r;
        vbase[(size_t)(((jj >> 5) * 4 + cg) * 512) + ((jj >> 3) & 3) * 128 +
              c * 8 + (jj & 7)] = (f16)(acc[cg][r] + bb);
      }
    }
  } else if (wsel == 1) {
    // K fragment-major: Kf[bh][t][half][lane_f*8+e],
    // lane_f = qf*16 + (row within 16-tile), e = c&7.
    const int t = n >> 4;
    f16* kbase = Kf + (((size_t)bh2 * 256 + t) * 2) * 512;
#pragma unroll
    for (int cg = 0; cg < 4; ++cg) {
      float bb = bk[o0 + cg * 16 + c];
      const int half = cg >> 1;
      const int qf = ((cg & 1) * 16 + c) >> 3;
      f16* kb2 = kbase + half * 512 + qf * 128 + (c & 7);
#pragma unroll
      for (int r = 0; r < 4; ++r) kb2[(q * 4 + r) * 8] = (f16)(acc[cg][r] + bb);
    }
  } else {
    // Q keeps (n, dh) layout, pre-scaled by 1/8
#pragma unroll
    for (int cg = 0; cg < 4; ++cg) {
      int dh = cg * 16 + c;
      float bb = bq[o0 + dh];
#pragma unroll
      for (int r = 0; r < 4; ++r)
        Qh[((size_t)bh2 * N_ + n + q * 4 + r) * DH_ + dh] =
            (f16)((acc[cg][r] + bb) * 0.125f);
    }
  }
}

#define TS 68  // LDS p-tile row stride (f32); rows 16B-aligned (68*4=272=17*16)
#define WTILE (16 * TS)

// ---------------- pass A: row-sums (linv) + PV -> O ----------------
// grid = 1024 blocks: bh = gid&7 (XCD-pinned), i-block = gid>>3 (32 rows).
// Block = 4 waves = 4 j-quarters; each wave: 2 i-groups per K/V tile, each
// with its OWN LDS p-buffer so the two chains are independent: ig1's whole
// QK+exp phase sits between ig0's LDS writes and reads (hides ds RAW).
// V loads placed after ig0 (shorter live ranges -> target ~150 VGPR,
// 3 waves/SIMD vs R5's 2).
__global__ __launch_bounds__(256, 1) void attn_sum_kernel(
    const f16* __restrict__ Qh, const f16* __restrict__ Kf,
    const f16* __restrict__ Vf, const float* __restrict__ tau,
    const uint2* __restrict__ adjb, const float* __restrict__ cw,
    f16* __restrict__ Oh, float* __restrict__ rsum_ws) {
  __shared__ float lds[8 * WTILE];  // [wave][ig]
  __shared__ float lred[4][32];
  const int gid = blockIdx.x;
  const int bh = gid & 7;
  const int b = bh >> 2, h = bh & 3;
  const int i0 = (gid >> 3) * 32;
  const int tid = threadIdx.x;
  const int lane = tid & 63, jq = tid >> 6;
  const int q = lane >> 4, c = lane & 15;

  // Q fragments + tau for 2 i-groups
  f16x8 a0[2], a1[2];
  float tau_i[2][4];
#pragma unroll
  for (int ig = 0; ig < 2; ++ig) {
    const f16* Qbase = Qh + ((size_t)bh * N_ + i0 + ig * 16 + c) * DH_;
    a0[ig] = *(const f16x8*)(Qbase + q * 8);
    a1[ig] = *(const f16x8*)(Qbase + 32 + q * 8);
#pragma unroll
    for (int r = 0; r < 4; ++r)
      tau_i[ig][r] = tau[b * N_ + i0 + ig * 16 + q * 4 + r];
  }
  const float cw_h = cw[h];  // cb cancels in softmax
  const f16* Kfb = Kf + (size_t)bh * 262144 + lane * 8;
  const f16* Vfb = Vf + (size_t)bh * 262144 + lane * 8;
  const float* taub = tau + b * N_;
  const int jbase = jq * 1024;

  float lsum[2][4] = {};
  f32x4 oacc[2][4] = {};  // [ig][cg] - statically indexed everywhere
  float* myp0 = lds + (jq * 2) * WTILE;
  float* myp1 = myp0 + WTILE;

#pragma unroll 1
  for (int it = 0; it < 16; ++it) {
    const int j0 = jbase + it * 64;
    // ==== K fragments (8 contiguous 1 KB bursts) + tau_j ====
    f16x8 kf[8];
    {
      const f16* kt = Kfb + (size_t)(j0 >> 4) * 1024;
#pragma unroll
      for (int f = 0; f < 8; ++f) kf[f] = *(const f16x8*)(kt + f * 512);
    }
    float tj[4];
#pragma unroll
    for (int cg = 0; cg < 4; ++cg) tj[cg] = taub[j0 + cg * 16 + c];

    // ==== ig0: QK^T -> e -> myp0 ====
    {
      uint2 aw[4];
#pragma unroll
      for (int r = 0; r < 4; ++r)
        aw[r] = adjb[(size_t)(i0 + q * 4 + r) * 64 + (j0 >> 6)];
#pragma unroll
      for (int cg = 0; cg < 4; ++cg) {
        f32x4 s = {};
        s = __builtin_amdgcn_mfma_f32_16x16x32_f16(a0[0], kf[2 * cg], s, 0, 0, 0);
        s = __builtin_amdgcn_mfma_f32_16x16x32_f16(a1[0], kf[2 * cg + 1], s, 0, 0, 0);
        const float credj = cw_h * tj[cg];
        const unsigned shift = (cg & 1) * 16 + c;
#pragma unroll
        for (int r = 0; r < 4; ++r) {
          unsigned mword = (cg < 2) ? aw[r].x : aw[r].y;
          float e = __expf(s[r] + credj * tau_i[0][r]);
          e = ((mword >> shift) & 1) ? e : 0.f;
          lsum[0][r] += e;
          myp0[(q * 4 + r) * TS + cg * 16 + c] = e;
        }
      }
    }
    // ==== V fragments issued here: latency covered by ig1's QK+exp ====
    f16x8 vf[8];
    {
      const f16* vt = Vfb + (size_t)(j0 >> 6) * 4096;
#pragma unroll
      for (int f = 0; f < 8; ++f) vf[f] = *(const f16x8*)(vt + f * 512);
    }
    // ==== ig1: QK^T -> e -> myp1 ====
    {
      uint2 aw[4];
#pragma unroll
      for (int r = 0; r < 4; ++r)
        aw[r] = adjb[(size_t)(i0 + 16 + q * 4 + r) * 64 + (j0 >> 6)];
#pragma unroll
      for (int cg = 0; cg < 4; ++cg) {
        f32x4 s = {};
        s = __builtin_amdgcn_mfma_f32_16x16x32_f16(a0[1], kf[2 * cg], s, 0, 0, 0);
        s = __builtin_amdgcn_mfma_f32_16x16x32_f16(a1[1], kf[2 * cg + 1], s, 0, 0, 0);
        const float credj = cw_h * tj[cg];
        const unsigned shift = (cg & 1) * 16 + c;
#pragma unroll
        for (int r = 0; r < 4; ++r) {
          unsigned mword = (cg < 2) ? aw[r].x : aw[r].y;
          float e = __expf(s[r] + credj * tau_i[1][r]);
          e = ((mword >> shift) & 1) ? e : 0.f;
          lsum[1][r] += e;
          myp1[(q * 4 + r) * TS + cg * 16 + c] = e;
        }
      }
    }
    // ==== PV both igs (ig0's RAW long since satisfied) ====
#pragma unroll
    for (int ig = 0; ig < 2; ++ig) {
      float* myp = ig ? myp1 : myp0;
#pragma unroll
      for (int ks = 0; ks < 2; ++ks) {
        f32x4 plo = *(f32x4*)(myp + c * TS + ks * 32 + q * 8);
        f32x4 phi = *(f32x4*)(myp + c * TS + ks * 32 + q * 8 + 4);
        f16x8 pa;
#pragma unroll
        for (int t = 0; t < 4; ++t) {
          pa[t] = (f16)plo[t];
          pa[4 + t] = (f16)phi[t];
        }
#pragma unroll
        for (int cg = 0; cg < 4; ++cg)
          oacc[ig][cg] = __builtin_amdgcn_mfma_f32_16x16x32_f16(
              pa, vf[ks * 4 + cg], oacc[ig][cg], 0, 0, 0);
      }
    }
  }

  // ---- combine row sums across j-quarters -> lred ----
#pragma unroll
  for (int ig = 0; ig < 2; ++ig) {
#pragma unroll
    for (int r = 0; r < 4; ++r) {
      float v = lsum[ig][r];
      v += __shfl_xor(v, 1);
      v += __shfl_xor(v, 2);
      v += __shfl_xor(v, 4);
      v += __shfl_xor(v, 8);
      lsum[ig][r] = v;
    }
  }
  if (c == 0) {
#pragma unroll
    for (int ig = 0; ig < 2; ++ig)
#pragma unroll
      for (int r = 0; r < 4; ++r) lred[jq][ig * 16 + q * 4 + r] = lsum[ig][r];
  }
  __syncthreads();

  // ---- per-ig PV combine + O write (fully unrolled, static oacc index) ----
#pragma unroll
  for (int ig = 0; ig < 2; ++ig) {
    float linv[4];
#pragma unroll
    for (int r = 0; r < 4; ++r) {
      int row = ig * 16 + q * 4 + r;
      linv[r] = 1.0f / (lred[0][row] + lred[1][row] + lred[2][row] +
                        lred[3][row]);
    }
    if (jq == 0 && c == 0) {
#pragma unroll
      for (int r = 0; r < 4; ++r)
        rsum_ws[bh * N_ + i0 + ig * 16 + q * 4 + r] = linv[r];
    }
    if (jq != 0) {
#pragma unroll
      for (int cg = 0; cg < 4; ++cg)
#pragma unroll
        for (int r = 0; r < 4; ++r) myp0[(cg * 4 + r) * 64 + lane] = oacc[ig][cg][r];
    }
    __syncthreads();
    if (jq == 0) {
#pragma unroll
      for (int cg = 0; cg < 4; ++cg)
#pragma unroll
        for (int r = 0; r < 4; ++r) {
          float v = oacc[ig][cg][r];
#pragma unroll
          for (int jj = 1; jj < 4; ++jj)
            v += lds[(jj * 2) * WTILE + (cg * 4 + r) * 64 + lane];
          Oh[((size_t)(b * N_) + i0 + ig * 16 + q * 4 + r) * H_ + h * 64 +
             cg * 16 + c] = (f16)(v * linv[r]);
        }
    }
    __syncthreads();
  }
}

// ---------------- pass B: head-mean via QK^T recompute ----------------
// grid = 1024: gid&1 = b, (gid>>1)&3 = jq (gid&7 XCD-pinned), gid>>3 = i-block
// (32 rows). Per j-tile the 4 heads are unrolled with FULL ping-pong prefetch
// of both K-fragments and Q-fragments (buffer index h&1 is compile-time under
// the unroll -> no scratch): head h's loads issue during head h-1's MFMA+exp.
__global__ __launch_bounds__(256, 1) void attn_mean_kernel(
    const f16* __restrict__ Qh, const f16* __restrict__ Kf,
    const float* __restrict__ tau, const uint2* __restrict__ adjb,
    const float* __restrict__ cw, const float* __restrict__ linv_ws,
    float* __restrict__ out) {
  const int gid = blockIdx.x;
  const int b = gid & 1;
  const int jq = (gid >> 1) & 3;
  const int i0 = (gid >> 3) * 32;
  const int tid = threadIdx.x;
  const int lane = tid & 63, w = tid >> 6;
  const int q = lane >> 4, c = lane & 15;

  // per-row linv*0.25 for all 4 heads x 2 i-groups (held in registers)
  float li[4][2][4];
  float cwh[4];
#pragma unroll
  for (int h = 0; h < 4; ++h) {
    cwh[h] = cw[h];
#pragma unroll
    for (int ig = 0; ig < 2; ++ig)
#pragma unroll
      for (int r = 0; r < 4; ++r)
        li[h][ig][r] =
            linv_ws[(b * 4 + h) * N_ + i0 + ig * 16 + q * 4 + r] * 0.25f;
  }
  float tau_i[2][4];
#pragma unroll
  for (int ig = 0; ig < 2; ++ig)
#pragma unroll
    for (int r = 0; r < 4; ++r)
      tau_i[ig][r] = tau[b * N_ + i0 + ig * 16 + q * 4 + r];
  const float* taub = tau + b * N_;
  // head strides: Kf and Qh both 262144 f16 per head
  const f16* KfB = Kf + (size_t)(b * 4) * 262144 + lane * 8;
  const f16* QB = Qh + ((size_t)(b * 4) * N_ + i0 + c) * DH_;

  // ping-pong K and Q fragment buffers
  f16x8 kf2[2][8];
  f16x8 qa[2][2][2];  // [ping][ig][half]
  {
    const int j0 = jq * 1024 + (0 * 4 + w) * 64;
    const f16* kt = KfB + (size_t)(j0 >> 4) * 1024;
#pragma unroll
    for (int f = 0; f < 8; ++f) kf2[0][f] = *(const f16x8*)(kt + f * 512);
#pragma unroll
    for (int ig = 0; ig < 2; ++ig) {
      qa[0][ig][0] = *(const f16x8*)(QB + ig * 1024 + q * 8);
      qa[0][ig][1] = *(const f16x8*)(QB + ig * 1024 + 32 + q * 8);
    }
  }

#pragma unroll 1
  for (int it = 0; it < 4; ++it) {
    const int j0 = jq * 1024 + (it * 4 + w) * 64;
    uint2 aw[2][4];
#pragma unroll
    for (int ig = 0; ig < 2; ++ig)
#pragma unroll
      for (int r = 0; r < 4; ++r)
        aw[ig][r] = adjb[(size_t)(i0 + ig * 16 + q * 4 + r) * 64 + (j0 >> 6)];
    float tj[4];
#pragma unroll
    for (int cg = 0; cg < 4; ++cg) tj[cg] = taub[j0 + cg * 16 + c];

    f32x4 macc[2][4] = {};  // [ig][cg]
#pragma unroll
    for (int h = 0; h < 4; ++h) {
      const int cur = h & 1, nx = cur ^ 1;
      // prefetch next (head, tile): next head of this tile, or head 0 of the
      // next tile (last tile: harmless redundant reload of the same data)
      {
        const int hn = (h + 1) & 3;
        const int itn = (h < 3) ? it : (it < 3 ? it + 1 : it);
        const int j0n = jq * 1024 + (itn * 4 + w) * 64;
        const f16* ktn = KfB + (size_t)hn * 262144 + (size_t)(j0n >> 4) * 1024;
#pragma unroll
        for (int f = 0; f < 8; ++f) kf2[nx][f] = *(const f16x8*)(ktn + f * 512);
        const f16* qn = QB + (size_t)hn * 262144;
#pragma unroll
        for (int ig = 0; ig < 2; ++ig) {
          qa[nx][ig][0] = *(const f16x8*)(qn + ig * 1024 + q * 8);
          qa[nx][ig][1] = *(const f16x8*)(qn + ig * 1024 + 32 + q * 8);
        }
      }
      // compute with current buffers
#pragma unroll
      for (int ig = 0; ig < 2; ++ig) {
#pragma unroll
        for (int cg = 0; cg < 4; ++cg) {
          f32x4 s = {};
          s = __builtin_amdgcn_mfma_f32_16x16x32_f16(qa[cur][ig][0],
                                                     kf2[cur][2 * cg], s, 0, 0, 0);
          s = __builtin_amdgcn_mfma_f32_16x16x32_f16(
              qa[cur][ig][1], kf2[cur][2 * cg + 1], s, 0, 0, 0);
          const float credj = cwh[h] * tj[cg];
          const unsigned shift = (cg & 1) * 16 + c;
#pragma unroll
          for (int r = 0; r < 4; ++r) {
            unsigned mword = (cg < 2) ? aw[ig][r].x : aw[ig][r].y;
            float e = __expf(s[r] + credj * tau_i[ig][r]);
            float lw = ((mword >> shift) & 1) ? li[h][ig][r] : 0.f;
            macc[ig][cg][r] += e * lw;
          }
        }
      }
    }
    // direct store of the 32x64 f32 mean tile (16-lane rows = full 64 B lines)
#pragma unroll
    for (int ig = 0; ig < 2; ++ig)
#pragma unroll
      for (int cg = 0; cg < 4; ++cg)
#pragma unroll
        for (int r = 0; r < 4; ++r)
          out[((size_t)(b * N_) + i0 + ig * 16 + q * 4 + r) * N_ + j0 +
              cg * 16 + c] = macc[ig][cg][r];
  }
}

// Output projection: h_out = O @ Wo^T + bo. grid=(128,4), block=4 waves, 64x64 tile.
__global__ __launch_bounds__(256) void oproj_kernel(
    const f16* __restrict__ Oh, const f16* __restrict__ Woh,
    const float* __restrict__ bo, float* __restrict__ out) {
  const int tid = threadIdx.x, lane = tid & 63, w = tid >> 6;
  const int q = lane >> 4, c = lane & 15;
  const int m0 = blockIdx.x * 64 + w * 16;
  const int o0 = blockIdx.y * 64;
  f32x4 acc[4] = {};
  for (int k0 = 0; k0 < 256; k0 += 32) {
    f16x8 a = *(const f16x8*)(Oh + (size_t)(m0 + c) * 256 + k0 + q * 8);
#pragma unroll
    for (int cg = 0; cg < 4; ++cg) {
      f16x8 bfr = *(const f16x8*)(Woh + (size_t)(o0 + cg * 16 + c) * 256 + k0 + q * 8);
      acc[cg] = __builtin_amdgcn_mfma_f32_16x16x32_f16(a, bfr, acc[cg], 0, 0, 0);
    }
  }
#pragma unroll
  for (int cg = 0; cg < 4; ++cg) {
    float bb = bo[o0 + cg * 16 + c];
#pragma unroll
    for (int r = 0; r < 4; ++r)
      out[(size_t)(m0 + q * 4 + r) * 256 + o0 + cg * 16 + c] = acc[cg][r] + bb;
  }
}

extern "C" void kernel_launch(void* const* d_in, const int* in_sizes, int n_in,
                              void* d_out, int out_size, void* d_ws,
                              size_t ws_size, hipStream_t stream) {
  const float* h   = (const float*)d_in[0];
  const float* tau = (const float*)d_in[1];
  const int*   adj = (const int*)d_in[2];
  const float* Wq  = (const float*)d_in[3];
  const float* bq  = (const float*)d_in[4];
  const float* Wk  = (const float*)d_in[5];
  const float* bk  = (const float*)d_in[6];
  const float* Wv  = (const float*)d_in[7];
  const float* bv  = (const float*)d_in[8];
  const float* cw  = (const float*)d_in[9];
  const float* Wo  = (const float*)d_in[11];
  const float* bo  = (const float*)d_in[12];
  float* out = (float*)d_out;

  f16* ws   = (f16*)d_ws;
  f16* h_h  = ws;
  f16* W_h  = ws + 2097152;
  f16* Wo_h = W_h + 3 * 65536;
  f16* Q_h  = ws + 2359296;
  f16* K_f  = ws + 4456448;
  f16* V_f  = ws + 6553600;
  f16* O_h  = ws + 8650752;
  unsigned long long* adjb = (unsigned long long*)(ws + 10747904);
  float* rsum_ws = (float*)ws;  // reuses dead h_h region (proj runs before attn)

  pack_adj_kernel<<<dim3(65536), dim3(256), 0, stream>>>(adj, adjb);
  cvt_kernel<<<dim3(9216), dim3(256), 0, stream>>>(h, Wq, Wk, Wv, Wo, ws);
  proj_kernel<<<dim3(128, 12), dim3(256), 0, stream>>>(h_h, W_h, bq, bk, bv, Q_h,
                                                       K_f, V_f);
  attn_sum_kernel<<<dim3(1024), dim3(256), 0, stream>>>(
      Q_h, K_f, V_f, tau, (const uint2*)adjb, cw, O_h, rsum_ws);
  attn_mean_kernel<<<dim3(1024), dim3(256), 0, stream>>>(
      Q_h, K_f, tau, (const uint2*)adjb, cw, rsum_ws, out + HOUT_OFF);
  oproj_kernel<<<dim3(128, 4), dim3(256), 0, stream>>>(O_h, Wo_h, bo, out);
}

// Round 7
// 386.696 us; speedup vs baseline: 1.0710x; 1.0710x over previous
//
#include <hip/hip_runtime.h>

// Problem constants
#define B_ 2
#define N_ 4096
#define H_ 256
#define HEADS_ 4
#define DH_ 64

typedef _Float16 f16;
typedef f16 f16x8 __attribute__((ext_vector_type(8)));
typedef f16 f16x4 __attribute__((ext_vector_type(4)));
typedef float f32x4 __attribute__((ext_vector_type(4)));

// Workspace layout (units: f16 elements)
//  h_h  : 0         2097152   (dead after proj; rsum_ws f32 reuses this region)
//  W_h  : 2097152   4*65536 (Wq,Wk,Wv,Wo)
//  Q_h  : 2359296   2097152   (b,head,n,dh), pre-scaled by 1/8
//  Kf   : 4456448   2097152   fragment-major K: [bh][t][half] 512-f16 frags
//  Vf   : 6553600   2097152   fragment-major V: [bh][jt][ks*4+cg] 512-f16 frags
//  O_h  : 8650752   2097152   (b,n,256)
//  adjb : 10747904  1048576   2 MB packed adjacency bitmask
// total ~24 MB

#define HOUT_OFF 2097152  // float offset of attn part in d_out

__global__ __launch_bounds__(256) void cvt_kernel(
    const float* __restrict__ h, const float* __restrict__ Wq,
    const float* __restrict__ Wk, const float* __restrict__ Wv,
    const float* __restrict__ Wo, f16* __restrict__ ws) {
  int i = blockIdx.x * 256 + threadIdx.x;
  const int NH = 2097152;
  if (i < NH) {
    ws[i] = (f16)h[i];
  } else if (i < NH + 4 * 65536) {
    int j = i - NH;
    int sel = j >> 16;
    int k = j & 65535;
    const float* src = sel == 0 ? Wq : sel == 1 ? Wk : sel == 2 ? Wv : Wo;
    ws[i] = (f16)src[k];
  }
}

// Pack adj (int32 0/1, NxN) into bit-mask, u16 granularity:
// adjp[row*256 + col16] bit b = adj[row][col16*16+b]. Little-endian u16s
// compose the same u64 words the attention kernels read as uint2.
// 16 ints per thread via 4x int4 (64 B contiguous per thread, coalesced).
__global__ __launch_bounds__(256) void pack_adj_kernel(
    const int4* __restrict__ adj4, unsigned short* __restrict__ adjp) {
  int g = blockIdx.x * 256 + threadIdx.x;  // 1M threads, grid 4096
  const int4* base = adj4 + (size_t)g * 4;
  unsigned m = 0;
#pragma unroll
  for (int t = 0; t < 4; ++t) {
    int4 v = base[t];
    m |= (unsigned)(v.x != 0) << (4 * t);
    m |= (unsigned)(v.y != 0) << (4 * t + 1);
    m |= (unsigned)(v.z != 0) << (4 * t + 2);
    m |= (unsigned)(v.w != 0) << (4 * t + 3);
  }
  adjp[g] = (unsigned short)m;
}

// QKV projection. grid=(128, 12): y = wsel*4 + head. Block = 4 waves, tile 64x64.
// K and V are written in FRAGMENT-MAJOR layout so attention waves load them as
// contiguous 1 KB bursts (lane*8) instead of 16-line scattered reads.
__global__ __launch_bounds__(256) void proj_kernel(
    const f16* __restrict__ hh, const f16* __restrict__ Wh,
    const float* __restrict__ bq, const float* __restrict__ bk,
    const float* __restrict__ bv, f16* __restrict__ Qh, f16* __restrict__ Kf,
    f16* __restrict__ Vf) {
  const int tid = threadIdx.x;
  const int lane = tid & 63, w = tid >> 6;
  const int q = lane >> 4, c = lane & 15;
  const int wsel = blockIdx.y >> 2, head = blockIdx.y & 3;
  const int m0 = blockIdx.x * 64 + w * 16;
  const f16* W = Wh + wsel * 65536;
  const int o0 = head * 64;

  f32x4 acc[4] = {};
  for (int k0 = 0; k0 < 256; k0 += 32) {
    f16x8 a = *(const f16x8*)(hh + (size_t)(m0 + c) * 256 + k0 + q * 8);
#pragma unroll
    for (int cg = 0; cg < 4; ++cg) {
      f16x8 bfr = *(const f16x8*)(W + (size_t)(o0 + cg * 16 + c) * 256 + k0 + q * 8);
      acc[cg] = __builtin_amdgcn_mfma_f32_16x16x32_f16(a, bfr, acc[cg], 0, 0, 0);
    }
  }
  const int b = m0 >> 12, n = m0 & 4095;
  const int bh2 = b * HEADS_ + head;
  if (wsel == 2) {
    // V fragment-major: Vf[bh][jt][ks*4+cg][lane_f*8+e],
    // lane_f=(jj>>3&3)*16+c, jj = j mod 64, e = jj&7.
    const int jt = n >> 6;
    f16* vbase = Vf + (((size_t)bh2 * 64 + jt) * 8) * 512;
#pragma unroll
    for (int cg = 0; cg < 4; ++cg) {
      float bb = bv[o0 + cg * 16 + c];
#pragma unroll
      for (int r = 0; r < 4; ++r) {
        int jj = w * 16 + q * 4 + r;
        vbase[(size_t)(((jj >> 5) * 4 + cg) * 512) + ((jj >> 3) & 3) * 128 +
              c * 8 + (jj & 7)] = (f16)(acc[cg][r] + bb);
      }
    }
  } else if (wsel == 1) {
    // K fragment-major: Kf[bh][t][half][lane_f*8+e],
    // lane_f = qf*16 + (row within 16-tile), e = c&7.
    const int t = n >> 4;
    f16* kbase = Kf + (((size_t)bh2 * 256 + t) * 2) * 512;
#pragma unroll
    for (int cg = 0; cg < 4; ++cg) {
      float bb = bk[o0 + cg * 16 + c];
      const int half = cg >> 1;
      const int qf = ((cg & 1) * 16 + c) >> 3;
      f16* kb2 = kbase + half * 512 + qf * 128 + (c & 7);
#pragma unroll
      for (int r = 0; r < 4; ++r) kb2[(q * 4 + r) * 8] = (f16)(acc[cg][r] + bb);
    }
  } else {
    // Q keeps (n, dh) layout, pre-scaled by 1/8
#pragma unroll
    for (int cg = 0; cg < 4; ++cg) {
      int dh = cg * 16 + c;
      float bb = bq[o0 + dh];
#pragma unroll
      for (int r = 0; r < 4; ++r)
        Qh[((size_t)bh2 * N_ + n + q * 4 + r) * DH_ + dh] =
            (f16)((acc[cg][r] + bb) * 0.125f);
    }
  }
}

#define TSH 80  // f16 P-tile row stride: 160 B rows, 16 B aligned, ~2-way banks
#define PTILE (16 * TSH)

// ---------------- pass A: row-sums (linv) + PV -> O ----------------
// grid = 1024 blocks: bh = gid&7 (XCD-pinned), i-block = gid>>3 (32 rows).
// 4 waves = 4 j-quarters; 2 i-groups per K/V tile, each with its own f16
// LDS P-buffer: ig1's QK+exp phase sits between ig0's LDS writes and reads.
// e stored DIRECTLY as f16 (one cvt at production); PV reads f16x8 A-operand
// straight from LDS — removes the f32 round-trip + 32 cvts per iter (R6 was
// VALU-bound at 51% busy).
__global__ __launch_bounds__(256, 1) void attn_sum_kernel(
    const f16* __restrict__ Qh, const f16* __restrict__ Kf,
    const f16* __restrict__ Vf, const float* __restrict__ tau,
    const uint2* __restrict__ adjb, const float* __restrict__ cw,
    f16* __restrict__ Oh, float* __restrict__ rsum_ws) {
  __shared__ f16 ptile[8 * PTILE];   // [wave][ig] 20 KB
  __shared__ float ocomb[4][1024];   // PV cross-wave combine, 16 KB
  __shared__ float lred[4][32];
  const int gid = blockIdx.x;
  const int bh = gid & 7;
  const int b = bh >> 2, h = bh & 3;
  const int i0 = (gid >> 3) * 32;
  const int tid = threadIdx.x;
  const int lane = tid & 63, jq = tid >> 6;
  const int q = lane >> 4, c = lane & 15;

  // Q fragments + tau for 2 i-groups
  f16x8 a0[2], a1[2];
  float tau_i[2][4];
#pragma unroll
  for (int ig = 0; ig < 2; ++ig) {
    const f16* Qbase = Qh + ((size_t)bh * N_ + i0 + ig * 16 + c) * DH_;
    a0[ig] = *(const f16x8*)(Qbase + q * 8);
    a1[ig] = *(const f16x8*)(Qbase + 32 + q * 8);
#pragma unroll
    for (int r = 0; r < 4; ++r)
      tau_i[ig][r] = tau[b * N_ + i0 + ig * 16 + q * 4 + r];
  }
  const float cw_h = cw[h];  // cb cancels in softmax
  const f16* Kfb = Kf + (size_t)bh * 262144 + lane * 8;
  const f16* Vfb = Vf + (size_t)bh * 262144 + lane * 8;
  const float* taub = tau + b * N_;
  const int jbase = jq * 1024;

  float lsum[2][4] = {};
  f32x4 oacc[2][4] = {};  // [ig][cg] - statically indexed everywhere
  f16* myp0 = ptile + (jq * 2) * PTILE;
  f16* myp1 = myp0 + PTILE;

#pragma unroll 1
  for (int it = 0; it < 16; ++it) {
    const int j0 = jbase + it * 64;
    // ==== K fragments (8 contiguous 1 KB bursts) + tau_j ====
    f16x8 kf[8];
    {
      const f16* kt = Kfb + (size_t)(j0 >> 4) * 1024;
#pragma unroll
      for (int f = 0; f < 8; ++f) kf[f] = *(const f16x8*)(kt + f * 512);
    }
    float tj[4];
#pragma unroll
    for (int cg = 0; cg < 4; ++cg) tj[cg] = taub[j0 + cg * 16 + c];

    // ==== ig0: QK^T -> e (f16) -> myp0 ====
    {
      uint2 aw[4];
#pragma unroll
      for (int r = 0; r < 4; ++r)
        aw[r] = adjb[(size_t)(i0 + q * 4 + r) * 64 + (j0 >> 6)];
#pragma unroll
      for (int cg = 0; cg < 4; ++cg) {
        f32x4 s = {};
        s = __builtin_amdgcn_mfma_f32_16x16x32_f16(a0[0], kf[2 * cg], s, 0, 0, 0);
        s = __builtin_amdgcn_mfma_f32_16x16x32_f16(a1[0], kf[2 * cg + 1], s, 0, 0, 0);
        const float credj = cw_h * tj[cg];
        const unsigned shift = (cg & 1) * 16 + c;
#pragma unroll
        for (int r = 0; r < 4; ++r) {
          unsigned mword = (cg < 2) ? aw[r].x : aw[r].y;
          float e = __expf(s[r] + credj * tau_i[0][r]);
          e = ((mword >> shift) & 1) ? e : 0.f;
          lsum[0][r] += e;
          myp0[(q * 4 + r) * TSH + cg * 16 + c] = (f16)e;
        }
      }
    }
    // ==== V fragments issued here: latency covered by ig1's QK+exp ====
    f16x8 vf[8];
    {
      const f16* vt = Vfb + (size_t)(j0 >> 6) * 4096;
#pragma unroll
      for (int f = 0; f < 8; ++f) vf[f] = *(const f16x8*)(vt + f * 512);
    }
    // ==== ig1: QK^T -> e (f16) -> myp1 ====
    {
      uint2 aw[4];
#pragma unroll
      for (int r = 0; r < 4; ++r)
        aw[r] = adjb[(size_t)(i0 + 16 + q * 4 + r) * 64 + (j0 >> 6)];
#pragma unroll
      for (int cg = 0; cg < 4; ++cg) {
        f32x4 s = {};
        s = __builtin_amdgcn_mfma_f32_16x16x32_f16(a0[1], kf[2 * cg], s, 0, 0, 0);
        s = __builtin_amdgcn_mfma_f32_16x16x32_f16(a1[1], kf[2 * cg + 1], s, 0, 0, 0);
        const float credj = cw_h * tj[cg];
        const unsigned shift = (cg & 1) * 16 + c;
#pragma unroll
        for (int r = 0; r < 4; ++r) {
          unsigned mword = (cg < 2) ? aw[r].x : aw[r].y;
          float e = __expf(s[r] + credj * tau_i[1][r]);
          e = ((mword >> shift) & 1) ? e : 0.f;
          lsum[1][r] += e;
          myp1[(q * 4 + r) * TSH + cg * 16 + c] = (f16)e;
        }
      }
    }
    // ==== PV both igs: A-operand read directly as f16x8 from LDS ====
#pragma unroll
    for (int ig = 0; ig < 2; ++ig) {
      const f16* myp = ig ? myp1 : myp0;
#pragma unroll
      for (int ks = 0; ks < 2; ++ks) {
        f16x8 pa = *(const f16x8*)(myp + c * TSH + ks * 32 + q * 8);
#pragma unroll
        for (int cg = 0; cg < 4; ++cg)
          oacc[ig][cg] = __builtin_amdgcn_mfma_f32_16x16x32_f16(
              pa, vf[ks * 4 + cg], oacc[ig][cg], 0, 0, 0);
      }
    }
  }

  // ---- combine row sums across j-quarters -> lred ----
#pragma unroll
  for (int ig = 0; ig < 2; ++ig) {
#pragma unroll
    for (int r = 0; r < 4; ++r) {
      float v = lsum[ig][r];
      v += __shfl_xor(v, 1);
      v += __shfl_xor(v, 2);
      v += __shfl_xor(v, 4);
      v += __shfl_xor(v, 8);
      lsum[ig][r] = v;
    }
  }
  if (c == 0) {
#pragma unroll
    for (int ig = 0; ig < 2; ++ig)
#pragma unroll
      for (int r = 0; r < 4; ++r) lred[jq][ig * 16 + q * 4 + r] = lsum[ig][r];
  }
  __syncthreads();

  // ---- per-ig PV combine + O write (fully unrolled, static oacc index) ----
#pragma unroll
  for (int ig = 0; ig < 2; ++ig) {
    float linv[4];
#pragma unroll
    for (int r = 0; r < 4; ++r) {
      int row = ig * 16 + q * 4 + r;
      linv[r] = 1.0f / (lred[0][row] + lred[1][row] + lred[2][row] +
                        lred[3][row]);
    }
    if (jq == 0 && c == 0) {
#pragma unroll
      for (int r = 0; r < 4; ++r)
        rsum_ws[bh * N_ + i0 + ig * 16 + q * 4 + r] = linv[r];
    }
    if (jq != 0) {
#pragma unroll
      for (int cg = 0; cg < 4; ++cg)
#pragma unroll
        for (int r = 0; r < 4; ++r)
          ocomb[jq][(cg * 4 + r) * 64 + lane] = oacc[ig][cg][r];
    }
    __syncthreads();
    if (jq == 0) {
#pragma unroll
      for (int cg = 0; cg < 4; ++cg)
#pragma unroll
        for (int r = 0; r < 4; ++r) {
          float v = oacc[ig][cg][r];
#pragma unroll
          for (int jj = 1; jj < 4; ++jj)
            v += ocomb[jj][(cg * 4 + r) * 64 + lane];
          Oh[((size_t)(b * N_) + i0 + ig * 16 + q * 4 + r) * H_ + h * 64 +
             cg * 16 + c] = (f16)(v * linv[r]);
        }
    }
    __syncthreads();
  }
}

// ---------------- pass B: head-mean via QK^T recompute ----------------
// grid = 2048: gid&1 = b, (gid>>1)&3 = jq (gid&7 XCD-pinned), gid>>3 = i-block
// (16 rows, ig=1). Flattened (it,h) step sequence with K+Q ping-pong prefetch.
// ig=1 slims live state (~155 VGPR target) -> 3 waves/SIMD vs R6's 2 at 192.
__global__ __launch_bounds__(256, 1) void attn_mean_kernel(
    const f16* __restrict__ Qh, const f16* __restrict__ Kf,
    const float* __restrict__ tau, const uint2* __restrict__ adjb,
    const float* __restrict__ cw, const float* __restrict__ linv_ws,
    float* __restrict__ out) {
  const int gid = blockIdx.x;
  const int b = gid & 1;
  const int jq = (gid >> 1) & 3;
  const int i0 = (gid >> 3) * 16;
  const int tid = threadIdx.x;
  const int lane = tid & 63, w = tid >> 6;
  const int q = lane >> 4, c = lane & 15;

  // per-row linv*0.25 for 4 heads (registers)
  float li[4][4];
  float cwh[4];
#pragma unroll
  for (int h = 0; h < 4; ++h) {
    cwh[h] = cw[h];
#pragma unroll
    for (int r = 0; r < 4; ++r)
      li[h][r] = linv_ws[(b * 4 + h) * N_ + i0 + q * 4 + r] * 0.25f;
  }
  float tau_i[4];
#pragma unroll
  for (int r = 0; r < 4; ++r) tau_i[r] = tau[b * N_ + i0 + q * 4 + r];
  const float* taub = tau + b * N_;
  const f16* KfB = Kf + (size_t)(b * 4) * 262144 + lane * 8;
  const f16* QB = Qh + ((size_t)(b * 4) * N_ + i0 + c) * DH_;

  // ping-pong K and Q fragment buffers (one (it,h) step each)
  f16x8 kf2[2][8];
  f16x8 qa2[2][2];
  {
    const int j0 = jq * 1024 + w * 64;
    const f16* kt = KfB + (size_t)(j0 >> 4) * 1024;
#pragma unroll
    for (int f = 0; f < 8; ++f) kf2[0][f] = *(const f16x8*)(kt + f * 512);
    qa2[0][0] = *(const f16x8*)(QB + q * 8);
    qa2[0][1] = *(const f16x8*)(QB + 32 + q * 8);
  }

#pragma unroll 1
  for (int it = 0; it < 4; ++it) {
    const int j0 = jq * 1024 + (it * 4 + w) * 64;
    uint2 aw[4];
#pragma unroll
    for (int r = 0; r < 4; ++r)
      aw[r] = adjb[(size_t)(i0 + q * 4 + r) * 64 + (j0 >> 6)];
    float tj[4];
#pragma unroll
    for (int cg = 0; cg < 4; ++cg) tj[cg] = taub[j0 + cg * 16 + c];

    f32x4 macc[4] = {};
#pragma unroll
    for (int h = 0; h < 4; ++h) {
      const int cur = h & 1, nx = cur ^ 1;
      // prefetch next (head, tile) step
      {
        const int hn = (h + 1) & 3;
        const int itn = (h < 3) ? it : (it < 3 ? it + 1 : it);
        const int j0n = jq * 1024 + (itn * 4 + w) * 64;
        const f16* ktn = KfB + (size_t)hn * 262144 + (size_t)(j0n >> 4) * 1024;
#pragma unroll
        for (int f = 0; f < 8; ++f) kf2[nx][f] = *(const f16x8*)(ktn + f * 512);
        const f16* qn = QB + (size_t)hn * 262144;
        qa2[nx][0] = *(const f16x8*)(qn + q * 8);
        qa2[nx][1] = *(const f16x8*)(qn + 32 + q * 8);
      }
      // compute with current buffers
#pragma unroll
      for (int cg = 0; cg < 4; ++cg) {
        f32x4 s = {};
        s = __builtin_amdgcn_mfma_f32_16x16x32_f16(qa2[cur][0], kf2[cur][2 * cg],
                                                   s, 0, 0, 0);
        s = __builtin_amdgcn_mfma_f32_16x16x32_f16(qa2[cur][1],
                                                   kf2[cur][2 * cg + 1], s, 0, 0, 0);
        const float credj = cwh[h] * tj[cg];
        const unsigned shift = (cg & 1) * 16 + c;
#pragma unroll
        for (int r = 0; r < 4; ++r) {
          unsigned mword = (cg < 2) ? aw[r].x : aw[r].y;
          float e = __expf(s[r] + credj * tau_i[r]);
          float lw = ((mword >> shift) & 1) ? li[h][r] : 0.f;
          macc[cg][r] += e * lw;
        }
      }
    }
    // direct store of the 16x64 f32 mean tile (16-lane rows = full 64 B lines)
#pragma unroll
    for (int cg = 0; cg < 4; ++cg)
#pragma unroll
      for (int r = 0; r < 4; ++r)
        out[((size_t)(b * N_) + i0 + q * 4 + r) * N_ + j0 + cg * 16 + c] =
            macc[cg][r];
  }
}

// Output projection: h_out = O @ Wo^T + bo. grid=(128,4), block=4 waves, 64x64 tile.
__global__ __launch_bounds__(256) void oproj_kernel(
    const f16* __restrict__ Oh, const f16* __restrict__ Woh,
    const float* __restrict__ bo, float* __restrict__ out) {
  const int tid = threadIdx.x, lane = tid & 63, w = tid >> 6;
  const int q = lane >> 4, c = lane & 15;
  const int m0 = blockIdx.x * 64 + w * 16;
  const int o0 = blockIdx.y * 64;
  f32x4 acc[4] = {};
  for (int k0 = 0; k0 < 256; k0 += 32) {
    f16x8 a = *(const f16x8*)(Oh + (size_t)(m0 + c) * 256 + k0 + q * 8);
#pragma unroll
    for (int cg = 0; cg < 4; ++cg) {
      f16x8 bfr = *(const f16x8*)(Woh + (size_t)(o0 + cg * 16 + c) * 256 + k0 + q * 8);
      acc[cg] = __builtin_amdgcn_mfma_f32_16x16x32_f16(a, bfr, acc[cg], 0, 0, 0);
    }
  }
#pragma unroll
  for (int cg = 0; cg < 4; ++cg) {
    float bb = bo[o0 + cg * 16 + c];
#pragma unroll
    for (int r = 0; r < 4; ++r)
      out[(size_t)(m0 + q * 4 + r) * 256 + o0 + cg * 16 + c] = acc[cg][r] + bb;
  }
}

extern "C" void kernel_launch(void* const* d_in, const int* in_sizes, int n_in,
                              void* d_out, int out_size, void* d_ws,
                              size_t ws_size, hipStream_t stream) {
  const float* h   = (const float*)d_in[0];
  const float* tau = (const float*)d_in[1];
  const int*   adj = (const int*)d_in[2];
  const float* Wq  = (const float*)d_in[3];
  const float* bq  = (const float*)d_in[4];
  const float* Wk  = (const float*)d_in[5];
  const float* bk  = (const float*)d_in[6];
  const float* Wv  = (const float*)d_in[7];
  const float* bv  = (const float*)d_in[8];
  const float* cw  = (const float*)d_in[9];
  const float* Wo  = (const float*)d_in[11];
  const float* bo  = (const float*)d_in[12];
  float* out = (float*)d_out;

  f16* ws   = (f16*)d_ws;
  f16* h_h  = ws;
  f16* W_h  = ws + 2097152;
  f16* Wo_h = W_h + 3 * 65536;
  f16* Q_h  = ws + 2359296;
  f16* K_f  = ws + 4456448;
  f16* V_f  = ws + 6553600;
  f16* O_h  = ws + 8650752;
  unsigned long long* adjb = (unsigned long long*)(ws + 10747904);
  float* rsum_ws = (float*)ws;  // reuses dead h_h region (proj runs before attn)

  pack_adj_kernel<<<dim3(4096), dim3(256), 0, stream>>>(
      (const int4*)adj, (unsigned short*)adjb);
  cvt_kernel<<<dim3(9216), dim3(256), 0, stream>>>(h, Wq, Wk, Wv, Wo, ws);
  proj_kernel<<<dim3(128, 12), dim3(256), 0, stream>>>(h_h, W_h, bq, bk, bv, Q_h,
                                                       K_f, V_f);
  attn_sum_kernel<<<dim3(1024), dim3(256), 0, stream>>>(
      Q_h, K_f, V_f, tau, (const uint2*)adjb, cw, O_h, rsum_ws);
  attn_mean_kernel<<<dim3(2048), dim3(256), 0, stream>>>(
      Q_h, K_f, tau, (const uint2*)adjb, cw, rsum_ws, out + HOUT_OFF);
  oproj_kernel<<<dim3(128, 4), dim3(256), 0, stream>>>(O_h, Wo_h, bo, out);
}